// Round 10
// baseline (329.274 us; speedup 1.0000x reference)
//
#include <hip/hip_runtime.h>
#include <math.h>

// Problem constants
#define HH 16
#define BB 4
#define LL 4096
#define DD 1024
#define DK 64
#define MMF 256
#define EPSF 1e-6f
// orf scale: 64^-0.25 * log2(e)  (phi computed as exp2)
#define KSCALE (0.35355339059327373f * 1.4426950408889634f)
// norm scale: 1/(2*sqrt(64)) * log2(e)
#define NORMSCALE (0.0625f * 1.4426950408889634f)
#define NSPLIT 8
#define LCH (LL / NSPLIT)             // 512 rows of L per kv block

typedef __attribute__((ext_vector_type(8))) short bf16x8;
typedef __attribute__((ext_vector_type(4))) float f32x4;
typedef __attribute__((ext_vector_type(8))) unsigned short u16x8;

__device__ __forceinline__ unsigned short f2bf(float f) {
  union { float f; unsigned u; } v; v.f = f;
  unsigned r = v.u + 0x7FFF + ((v.u >> 16) & 1);   // RNE
  return (unsigned short)(r >> 16);
}
__device__ __forceinline__ float bf2f(unsigned short h) {
  union { unsigned u; float f; } v; v.u = ((unsigned)h) << 16;
  return v.f;
}
__device__ __forceinline__ f32x4 mfma16(bf16x8 a, bf16x8 b, f32x4 c) {
  return __builtin_amdgcn_mfma_f32_16x16x32_bf16(a, b, c, 0, 0, 0);
}
// async global->LDS, 16B per lane; dst is wave-uniform base (lane x16 implicit)
__device__ __forceinline__ void gload16(const unsigned short* g, unsigned short* l) {
  __builtin_amdgcn_global_load_lds(
      (const __attribute__((address_space(1))) void*)g,
      (__attribute__((address_space(3))) void*)l, 16, 0, 0);
}
// T2 swizzle for 64-element bf16 rows (element-index xor)
#define SWZ(row, col) ((col) ^ (((row) & 7) << 3))

// ---------------------------------------------------------------------------
// fp32 -> bf16 conversion (n multiple of 4)
// ---------------------------------------------------------------------------
__global__ __launch_bounds__(256) void cvt_bf16(
    const float* __restrict__ src, unsigned short* __restrict__ dst, int n) {
  int i = (blockIdx.x * 256 + threadIdx.x) * 4;
  if (i < n) {
    float4 v = *(const float4*)&src[i];
    ushort4 o;
    o.x = f2bf(v.x); o.y = f2bf(v.y); o.z = f2bf(v.z); o.w = f2bf(v.w);
    *(ushort4*)&dst[i] = o;
  }
}

// fused 4-way weight conversion, grid (1024, 4)
__global__ __launch_bounds__(256) void cvt_bf16_w(
    const float* __restrict__ W0, const float* __restrict__ W1,
    const float* __restrict__ W2, const float* __restrict__ W3,
    unsigned short* __restrict__ D0, unsigned short* __restrict__ D1,
    unsigned short* __restrict__ D2, unsigned short* __restrict__ D3) {
  const float* s;
  unsigned short* d;
  switch (blockIdx.y) {
    case 0: s = W0; d = D0; break;
    case 1: s = W1; d = D1; break;
    case 2: s = W2; d = D2; break;
    default: s = W3; d = D3; break;
  }
  int i = (blockIdx.x * 256 + threadIdx.x) * 4;
  float4 v = *(const float4*)&s[i];
  ushort4 o;
  o.x = f2bf(v.x); o.y = f2bf(v.y); o.z = f2bf(v.z); o.w = f2bf(v.w);
  *(ushort4*)&d[i] = o;
}

// orf: scale by KSCALE (dk^-.25 * log2e), split hi/lo bf16
__global__ __launch_bounds__(256) void cvt_orf(
    const float* __restrict__ src, unsigned short* __restrict__ hi,
    unsigned short* __restrict__ lo, int n) {
  int i = blockIdx.x * 256 + threadIdx.x;
  if (i < n) {
    float f = src[i] * KSCALE;
    unsigned short h = f2bf(f);
    hi[i] = h;
    lo[i] = f2bf(f - bf2f(h));
  }
}

// ---------------------------------------------------------------------------
// bf16 MFMA GEMM: C = A[M,K] @ W[N,K]^T + bias. 128x128 tile, BK=64, 4 waves.
// DOUBLE-BUFFERED LDS + counted vmcnt: next tile's 8 global_load_lds stay in
// flight across the compute phase (raw s_barrier; no vmcnt(0) drain in loop).
// Fixed shape M=16384, N=1024 -> grid 128x8, XCD-swizzled.
// Epilogue: per-wave LDS-transpose -> fully coalesced 16B vector stores.
// MODE 0: fp32 C row-major.
// MODE 1: bf16 transposed Ct[(b*16+h)*64+d][4096]                  (V path)
// MODE 2: hi/lo bf16 [bh][l][64] + norms[bh][l] (pre *log2e/16)    (Q,K paths)
// ---------------------------------------------------------------------------
template <int MODE>
__global__ __launch_bounds__(256) void gemm_mfma(
    const unsigned short* __restrict__ A, const unsigned short* __restrict__ W,
    const float* __restrict__ bias, float* __restrict__ Cf,
    unsigned short* __restrict__ C1, unsigned short* __restrict__ C2,
    float* __restrict__ Cn, int M, int N, int K) {
  // [A0 16KB | B0 16KB | A1 16KB | B1 16KB]; epilogue reuses front 34816 B
  __shared__ __align__(16) char smem[65536];
  unsigned short* S = (unsigned short*)smem;
  const int tid = threadIdx.x, lane = tid & 63;
  const int w = tid >> 6, wr = w >> 1, wc = w & 1;
  const int g = lane >> 4, li = lane & 15;
  // XCD swizzle: each XCD owns 16 contiguous M-panels x all 8 N-panels
  const int flat = blockIdx.y * gridDim.x + blockIdx.x;     // 0..1023
  const int xcd = flat & 7, loc = flat >> 3;
  const int m0 = ((xcd << 4) + (loc & 15)) * 128;
  const int n0 = (loc >> 4) * 128;

  f32x4 acc[4][4] = {};
  const int srow8 = lane >> 3;                    // row within 8-row group
  const int scol  = ((lane & 7) ^ srow8) << 3;    // pre-swizzled element col
  const unsigned short* Ag = A + (size_t)(m0 + w * 32 + srow8) * K + scol;
  const unsigned short* Wg = W + (size_t)(n0 + w * 32 + srow8) * K + scol;
  const int nt = K >> 6;

  // prologue: stage tile 0 into buffer 0
#pragma unroll
  for (int j = 0; j < 4; ++j) {
    gload16(Ag + (size_t)j * 8 * K, S + (w * 32 + j * 8) * 64);
    gload16(Wg + (size_t)j * 8 * K, S + 8192 + (w * 32 + j * 8) * 64);
  }

  for (int t = 0; t < nt; ++t) {
    const int co = (t & 1) << 14;           // current buffer (ushort offset)
    const int no = co ^ 16384;              // next buffer
    if (t + 1 < nt) {
      const int k1 = (t + 1) << 6;
#pragma unroll
      for (int j = 0; j < 4; ++j) {
        gload16(Ag + (size_t)j * 8 * K + k1, S + no + (w * 32 + j * 8) * 64);
        gload16(Wg + (size_t)j * 8 * K + k1, S + no + 8192 + (w * 32 + j * 8) * 64);
      }
      // wait only for the CURRENT tile's 8 loads; next 8 stay in flight
      asm volatile("s_waitcnt vmcnt(8)" ::: "memory");
    } else {
      asm volatile("s_waitcnt vmcnt(0)" ::: "memory");
    }
    __builtin_amdgcn_s_barrier();

    const int sx = (li & 7) << 3;
#pragma unroll
    for (int kk = 0; kk < 2; ++kk) {
      const int c = (kk * 32 + g * 8) ^ sx;
      bf16x8 af[4], bfr[4];
#pragma unroll
      for (int i = 0; i < 4; ++i)
        af[i] = *(const bf16x8*)&S[co + (wr * 64 + i * 16 + li) * 64 + c];
#pragma unroll
      for (int j = 0; j < 4; ++j)
        bfr[j] = *(const bf16x8*)&S[co + 8192 + (wc * 64 + j * 16 + li) * 64 + c];
#pragma unroll
      for (int i = 0; i < 4; ++i)
#pragma unroll
        for (int j = 0; j < 4; ++j)
          acc[i][j] = mfma16(af[i], bfr[j], acc[i][j]);
    }
    // ds_reads must COMPLETE before next iteration re-stages this buffer
    asm volatile("s_waitcnt lgkmcnt(0)" ::: "memory");
    __builtin_amdgcn_s_barrier();
  }

  // ---------------- epilogue: LDS transpose, coalesced stores ---------------
  float* ep = (float*)smem + w * (32 * 68);
  const int head = (n0 + wc * 64) >> 6;
  const int rbase = m0 + wr * 64;       // global row base of this wave's tile
  const int b = rbase >> 12;            // batch (tile never crosses b boundary)

  if (MODE == 2) {
#pragma unroll
    for (int jh = 0; jh < 2; ++jh) {
      // write half: local rows 0..31 = global rows jh*32..+31, all 64 cols
#pragma unroll
      for (int i2 = 0; i2 < 2; ++i2) {
        const int i = jh * 2 + i2;
#pragma unroll
        for (int j = 0; j < 4; ++j) {
          const float bz = bias[n0 + wc * 64 + j * 16 + li];
#pragma unroll
          for (int r = 0; r < 4; ++r)
            ep[(i2 * 16 + 4 * g + r) * 68 + j * 16 + li] = acc[i][j][r] + bz;
        }
      }
      // read half: lane -> (row = p*8 + lane>>3, chunk c = lane&7 of 8 f32)
      const int rrow = lane >> 3, cc = lane & 7;
#pragma unroll
      for (int p = 0; p < 4; ++p) {
        const int row = p * 8 + rrow;
        float v[8];
        *(f32x4*)&v[0] = *(const f32x4*)&ep[row * 68 + cc * 8];
        *(f32x4*)&v[4] = *(const f32x4*)&ep[row * 68 + cc * 8 + 4];
        float np = 0.f;
        u16x8 hv, lv;
#pragma unroll
        for (int e = 0; e < 8; ++e) {
          float vv = v[e];
          np += vv * vv;
          unsigned short h = f2bf(vv);
          hv[e] = h;
          lv[e] = f2bf(vv - bf2f(h));
        }
        const int lg = (rbase + jh * 32 + row) & 4095;
        const size_t rowb = (size_t)(b * 16 + head) * 4096 + lg;
        *(u16x8*)&C1[rowb * 64 + cc * 8] = hv;
        *(u16x8*)&C2[rowb * 64 + cc * 8] = lv;
        np += __shfl_xor(np, 1);
        np += __shfl_xor(np, 2);
        np += __shfl_xor(np, 4);
        if (cc == 0) Cn[rowb] = np * NORMSCALE;
      }
    }
  } else if (MODE == 1) {
#pragma unroll
    for (int jh = 0; jh < 2; ++jh) {
      // write half: LDS [32 d][68 l]; acc's 4 rows (l) contiguous -> b128
#pragma unroll
      for (int i = 0; i < 4; ++i)
#pragma unroll
        for (int j2 = 0; j2 < 2; ++j2) {
          const int j = jh * 2 + j2;
          const float bz = bias[n0 + wc * 64 + j * 16 + li];
          f32x4 t;
          t[0] = acc[i][j][0] + bz; t[1] = acc[i][j][1] + bz;
          t[2] = acc[i][j][2] + bz; t[3] = acc[i][j][3] + bz;
          *(f32x4*)&ep[(j2 * 16 + li) * 68 + i * 16 + 4 * g] = t;
        }
      // read half: lane -> (d = p*8 + lane>>3, chunk c = lane&7 of 8 l)
      const int rd = lane >> 3, cc = lane & 7;
#pragma unroll
      for (int p = 0; p < 4; ++p) {
        const int dl = p * 8 + rd;
        float v[8];
        *(f32x4*)&v[0] = *(const f32x4*)&ep[dl * 68 + cc * 8];
        *(f32x4*)&v[4] = *(const f32x4*)&ep[dl * 68 + cc * 8 + 4];
        u16x8 hv;
#pragma unroll
        for (int e = 0; e < 8; ++e) hv[e] = f2bf(v[e]);
        const int dh = jh * 32 + dl;
        const int lg = rbase & 4095;
        *(u16x8*)&C1[((size_t)(b * 16 + head) * 64 + dh) * 4096 + lg + cc * 8] = hv;
      }
    }
  } else {  // MODE 0: fp32 row-major
#pragma unroll
    for (int jh = 0; jh < 2; ++jh) {
#pragma unroll
      for (int i2 = 0; i2 < 2; ++i2) {
        const int i = jh * 2 + i2;
#pragma unroll
        for (int j = 0; j < 4; ++j) {
          const float bz = bias[n0 + wc * 64 + j * 16 + li];
#pragma unroll
          for (int r = 0; r < 4; ++r)
            ep[(i2 * 16 + 4 * g + r) * 68 + j * 16 + li] = acc[i][j][r] + bz;
        }
      }
      // read: lane -> (row = p*4 + lane>>4, chunk c = lane&15 of 4 f32)
      const int rrow = lane >> 4, cc = lane & 15;
#pragma unroll
      for (int p = 0; p < 8; ++p) {
        const int row = p * 4 + rrow;
        f32x4 v = *(const f32x4*)&ep[row * 68 + cc * 4];
        *(f32x4*)&Cf[(size_t)(rbase + jh * 32 + row) * 1024 + n0 + wc * 64 + cc * 4] = v;
      }
    }
  }
}

// ---------------------------------------------------------------------------
// kv + ksum. grid (64 bh, NSPLIT), 512 threads = 8 waves. Each wave owns
// 32 m-rows (2 passes of 16); all 8 waves share one staged K/V tile, so HBM
// traffic is unchanged while waves/CU doubles (16/CU, 50% cap). Single-buffer
// staging (dbuf proven neutral, r9): 3 gload16/wave per chunk.
// ---------------------------------------------------------------------------
__global__ __launch_bounds__(512, 4) void kv_mfma(
    const unsigned short* __restrict__ khi, const unsigned short* __restrict__ klo,
    const float* __restrict__ knorms, const unsigned short* __restrict__ vt,
    const unsigned short* __restrict__ orfhi, const unsigned short* __restrict__ orflo,
    float* __restrict__ pkv, float* __restrict__ pksum) {
  __shared__ __align__(16) unsigned short KsHi[64 * 64], KsLo[64 * 64];
  __shared__ __align__(16) unsigned short VT[64 * 64];         // 24 KB tiles
  __shared__ __align__(16) unsigned short KphiT[8][32 * 64];   // 32 KB (wave-priv)
  __shared__ float ns[512];                                    // 2 KB
  const int tid = threadIdx.x, lane = tid & 63, w = tid >> 6;  // w: 0..7
  const int g = lane >> 4, li = lane & 15;
  const int bh = blockIdx.x, sp = blockIdx.y;
  const int srow8 = lane >> 3;
  const int scol  = ((lane & 7) ^ srow8) << 3;
  const int sx = (li & 7) << 3;

  // orf fragments in registers: A-operand rows m = w*32 + p*16 + li
  bf16x8 oh[2][2], ol[2][2];
#pragma unroll
  for (int p = 0; p < 2; ++p)
#pragma unroll
    for (int kk = 0; kk < 2; ++kk) {
      const size_t o = (size_t)(w * 32 + p * 16 + li) * 64 + kk * 32 + g * 8;
      oh[p][kk] = *(const bf16x8*)&orfhi[o];
      ol[p][kk] = *(const bf16x8*)&orflo[o];
    }

  // all 512 chunk norms for this (bh, sp) slice, one load
  ns[tid] = knorms[(size_t)bh * 4096 + sp * LCH + tid];

  f32x4 kvacc[2][4] = {};
  float ksacc[2][4] = {};

  for (int c = 0; c < LCH / 64; ++c) {
    const int l0 = sp * LCH + c * 64;
    __syncthreads();   // previous chunk's readers done (also covers ns wr)
    {  // stage: wave w covers rows w*8 .. w*8+7 of each 64x64 tile
      const size_t kb = ((size_t)bh * 4096 + l0 + w * 8 + srow8) * 64 + scol;
      gload16(khi + kb, &KsHi[(w * 8) * 64]);
      gload16(klo + kb, &KsLo[(w * 8) * 64]);
      const size_t vb = ((size_t)bh * 64 + w * 8 + srow8) * 4096 + l0 + scol;
      gload16(vt + vb, &VT[(w * 8) * 64]);
    }
    __syncthreads();

#pragma unroll
    for (int p = 0; p < 2; ++p) {
      // projT[m][l], 3-term hi/lo split
      f32x4 pr[4] = {};
      __builtin_amdgcn_s_setprio(1);
#pragma unroll
      for (int kk = 0; kk < 2; ++kk) {
        const int cx = (kk * 32 + g * 8) ^ sx;
#pragma unroll
        for (int lf = 0; lf < 4; ++lf) {
          const bf16x8 bh2 = *(const bf16x8*)&KsHi[(lf * 16 + li) * 64 + cx];
          const bf16x8 bl2 = *(const bf16x8*)&KsLo[(lf * 16 + li) * 64 + cx];
          pr[lf] = mfma16(oh[p][kk], bh2, pr[lf]);
          pr[lf] = mfma16(oh[p][kk], bl2, pr[lf]);
          pr[lf] = mfma16(ol[p][kk], bh2, pr[lf]);
        }
      }
      __builtin_amdgcn_s_setprio(0);
      // phi (exp2) + ksum + KphiT (wave-private slab, swizzled)
#pragma unroll
      for (int lf = 0; lf < 4; ++lf) {
        const float nrm = ns[c * 64 + lf * 16 + li];
#pragma unroll
        for (int r = 0; r < 4; ++r) {
          float phi = exp2f(pr[lf][r] - nrm) + EPSF;
          ksacc[p][r] += phi;
          const int row = p * 16 + 4 * g + r;
          KphiT[w][row * 64 + SWZ(row, lf * 16 + li)] = f2bf(phi);
        }
      }
      // kv += KphiT . V^T (same-wave LDS dependence, no barrier)
      __builtin_amdgcn_s_setprio(1);
#pragma unroll
      for (int kk = 0; kk < 2; ++kk) {
        const int cx = (kk * 32 + g * 8) ^ sx;
        const bf16x8 a = *(const bf16x8*)&KphiT[w][(p * 16 + li) * 64 + cx];
#pragma unroll
        for (int df = 0; df < 4; ++df) {
          const bf16x8 bv = *(const bf16x8*)&VT[(df * 16 + li) * 64 + cx];
          kvacc[p][df] = mfma16(a, bv, kvacc[p][df]);
        }
      }
      __builtin_amdgcn_s_setprio(0);
    }
  }
  float* kvo = pkv + ((size_t)sp * 64 + bh) * (MMF * DK);
#pragma unroll
  for (int p = 0; p < 2; ++p)
#pragma unroll
    for (int df = 0; df < 4; ++df)
#pragma unroll
      for (int r = 0; r < 4; ++r)
        kvo[(w * 32 + p * 16 + 4 * g + r) * DK + df * 16 + li] = kvacc[p][df][r];

  float* kso = pksum + ((size_t)sp * 64 + bh) * MMF;
#pragma unroll
  for (int p = 0; p < 2; ++p)
#pragma unroll
    for (int r = 0; r < 4; ++r) {
      float s = ksacc[p][r];
      s += __shfl_xor(s, 1); s += __shfl_xor(s, 2);
      s += __shfl_xor(s, 4); s += __shfl_xor(s, 8);
      if (li == 0) kso[w * 32 + p * 16 + 4 * g + r] = s;
    }
}

// ---------------------------------------------------------------------------
// reduce partials; emit kv TRANSPOSED bf16 kvT[bh][d][m] + ksum fp32
// ---------------------------------------------------------------------------
__global__ __launch_bounds__(256) void reduce_parts(
    const float* __restrict__ pkv, unsigned short* __restrict__ kvT,
    const float* __restrict__ pks, float* __restrict__ ksg) {
  const int id = blockIdx.x * 256 + threadIdx.x;   // grid 1024 -> 262144
  {
    const int bh = id >> 12, rest = id & 4095;
    const int m0 = (rest >> 6) << 2, d = rest & 63;
    float s0 = 0.f, s1 = 0.f, s2 = 0.f, s3 = 0.f;
#pragma unroll
    for (int sp = 0; sp < NSPLIT; ++sp) {
      const float* p = pkv + (size_t)(sp * 64 + bh) * (MMF * DK) + d;
      s0 += p[(m0 + 0) * DK]; s1 += p[(m0 + 1) * DK];
      s2 += p[(m0 + 2) * DK]; s3 += p[(m0 + 3) * DK];
    }
    ushort4 o;
    o.x = f2bf(s0); o.y = f2bf(s1); o.z = f2bf(s2); o.w = f2bf(s3);
    *(ushort4*)&kvT[((size_t)bh * DK + d) * MMF + m0] = o;
  }
  if (id < 4096) {
    float4 s = {0.f, 0.f, 0.f, 0.f};
#pragma unroll
    for (int sp = 0; sp < NSPLIT; ++sp) {
      float4 v = *(const float4*)&pks[(size_t)sp * 64 * MMF + id * 4];
      s.x += v.x; s.y += v.y; s.z += v.z; s.w += v.w;
    }
    *(float4*)&ksg[id * 4] = s;
  }
}

// ---------------------------------------------------------------------------
// q_phi + num/den -> attn (bf16). grid (64 bh, 32 l-blocks), 512 threads.
// 2-term proj split (orf-lo dropped). Q frags / norms / ksums in registers;
// OHi + kvT resident in LDS (80KB exactly -> 2 blocks/CU); barrier-free loop.
// ---------------------------------------------------------------------------
__global__ __launch_bounds__(512, 4) void qattn_mfma(
    const unsigned short* __restrict__ qhi, const unsigned short* __restrict__ qlo,
    const float* __restrict__ qnorms,
    const unsigned short* __restrict__ orfhi,
    const unsigned short* __restrict__ kvT, const float* __restrict__ ksg,
    unsigned short* __restrict__ attn) {
  __shared__ __align__(16) unsigned short OHi[256 * 64];    // 32 KB
  __shared__ __align__(16) unsigned short KvTs[64 * 256];   // 32 KB
  __shared__ __align__(16) unsigned short Qphi[8][16 * 64]; // 16 KB  -> 80 KB total
  const int tid = threadIdx.x, lane = tid & 63, w = tid >> 6;   // w: 0..7
  const int g = lane >> 4, li = lane & 15;
  const int bh = blockIdx.x, lb = blockIdx.y;
  const int b = bh >> 4, h = bh & 15;
  const int srow8 = lane >> 3;
  const int scol  = ((lane & 7) ^ srow8) << 3;
  const int sx = (li & 7) << 3;

  // ---- one-time staging ----
#pragma unroll
  for (int q = 0; q < 4; ++q) {   // orf-hi: wave w stages rows w*32 .. w*32+31
    const size_t o = (size_t)(w * 32 + q * 8 + srow8) * 64 + scol;
    gload16(orfhi + o, &OHi[(w * 32 + q * 8) * 64]);
  }
  {  // kvT: 64 rows x 512B; 2 rows per gload; wave w stages rows w*8..w*8+7
    const int srow2 = lane >> 5;                  // 0..1
#pragma unroll
    for (int q = 0; q < 4; ++q) {
      const int d0 = w * 8 + q * 2, dr = d0 + srow2;
      gload16(kvT + ((size_t)bh * DK + dr) * MMF + (((lane & 31) ^ (dr & 7)) << 3),
              &KvTs[d0 * 256]);
    }
  }

  // registers: ksums, norms, Q fragments
  float ksr[4][4];
#pragma unroll
  for (int p = 0; p < 4; ++p)
#pragma unroll
    for (int mf = 0; mf < 4; ++mf)
      ksr[p][mf] = ksg[(size_t)bh * MMF + p * 64 + mf * 16 + li];
  const float4 nr =
      *(const float4*)&qnorms[(size_t)bh * 4096 + lb * 128 + w * 16 + 4 * g];
  bf16x8 qh[2], ql[2];
  {
    const size_t qr = ((size_t)bh * 4096 + lb * 128 + w * 16 + li) * 64 + g * 8;
    qh[0] = *(const bf16x8*)&qhi[qr];
    qh[1] = *(const bf16x8*)&qhi[qr + 32];
    ql[0] = *(const bf16x8*)&qlo[qr];
    ql[1] = *(const bf16x8*)&qlo[qr + 32];
  }
  __syncthreads();   // gload staging complete

  f32x4 numacc[4] = {};
  float denacc[4] = {};

#pragma unroll
  for (int p = 0; p < 4; ++p) {
    // proj[l][m], 2-term split (qh*oh + ql*oh)
    f32x4 pr[4] = {};
    __builtin_amdgcn_s_setprio(1);
#pragma unroll
    for (int kk = 0; kk < 2; ++kk) {
      const int cx = (kk * 32 + g * 8) ^ sx;
#pragma unroll
      for (int mf = 0; mf < 4; ++mf) {
        const int row = p * 64 + mf * 16 + li;
        const bf16x8 bh2 = *(const bf16x8*)&OHi[row * 64 + cx];
        pr[mf] = mfma16(qh[kk], bh2, pr[mf]);
        pr[mf] = mfma16(ql[kk], bh2, pr[mf]);
      }
    }
    __builtin_amdgcn_s_setprio(0);
    // phi (exp2), den partial, Qphi (wave-private, swizzled)
#pragma unroll
    for (int mf = 0; mf < 4; ++mf) {
      const float ks = ksr[p][mf];
#pragma unroll
      for (int r = 0; r < 4; ++r) {
        float phi = exp2f(pr[mf][r] - nr[r]) + EPSF;
        denacc[r] += phi * ks;
        const int row = 4 * g + r;
        Qphi[w][row * 64 + SWZ(row, mf * 16 + li)] = f2bf(phi);
      }
    }
    // num += Qphi . kvT (same-wave Qphi; KvTs stable)
    __builtin_amdgcn_s_setprio(1);
#pragma unroll
    for (int kk = 0; kk < 2; ++kk) {
      const int cx = (kk * 32 + g * 8) ^ sx;
      const bf16x8 a = *(const bf16x8*)&Qphi[w][li * 64 + cx];
#pragma unroll
      for (int df = 0; df < 4; ++df) {
        const bf16x8 bv = *(const bf16x8*)
            &KvTs[(df * 16 + li) * 256 + (((p * 8 + kk * 4 + g) ^ (li & 7)) << 3)];
        numacc[df] = mfma16(a, bv, numacc[df]);
      }
    }
    __builtin_amdgcn_s_setprio(0);
  }
  float den[4];
#pragma unroll
  for (int r = 0; r < 4; ++r) {
    float s = denacc[r];
    s += __shfl_xor(s, 1); s += __shfl_xor(s, 2);
    s += __shfl_xor(s, 4); s += __shfl_xor(s, 8);
    den[r] = s;
  }
  unsigned short* ab =
      attn + ((size_t)b * 4096 + lb * 128) * 1024 + h * 64;
#pragma unroll
  for (int df = 0; df < 4; ++df)
#pragma unroll
    for (int r = 0; r < 4; ++r)
      ab[(size_t)(w * 16 + 4 * g + r) * 1024 + df * 16 + li] =
          f2bf(numacc[df][r] / den[r]);
}

// ---------------------------------------------------------------------------
extern "C" void kernel_launch(void* const* d_in, const int* in_sizes, int n_in,
                              void* d_out, int out_size, void* d_ws, size_t ws_size,
                              hipStream_t stream) {
  (void)in_sizes; (void)n_in; (void)out_size; (void)ws_size;
  const float* x   = (const float*)d_in[0];
  const float* Wq  = (const float*)d_in[1];
  const float* bq  = (const float*)d_in[2];
  const float* Wk  = (const float*)d_in[3];
  const float* bk  = (const float*)d_in[4];
  const float* Wv  = (const float*)d_in[5];
  const float* bv  = (const float*)d_in[6];
  const float* Wo  = (const float*)d_in[7];
  const float* bo  = (const float*)d_in[8];
  const float* orf = (const float*)d_in[9];
  float* out = (float*)d_out;

  const size_t ND = (size_t)BB * LL * DD;   // 16,777,216
  char* base = (char*)d_ws;
  size_t off = 0;
  auto alloc = [&](size_t bytes) -> char* {
    char* p = base + off;
    off += (bytes + 255) & ~(size_t)255;
    return p;
  };
  unsigned short* wqbf   = (unsigned short*)alloc((size_t)DD * DD * 2);
  unsigned short* wkbf   = (unsigned short*)alloc((size_t)DD * DD * 2);
  unsigned short* wvbf   = (unsigned short*)alloc((size_t)DD * DD * 2);
  unsigned short* wobf   = (unsigned short*)alloc((size_t)DD * DD * 2);
  unsigned short* orfhi  = (unsigned short*)alloc((size_t)MMF * DK * 2);
  unsigned short* orflo  = (unsigned short*)alloc((size_t)MMF * DK * 2);
  unsigned short* xbf    = (unsigned short*)alloc(ND * 2);   // aliased by pkv
  unsigned short* qhi    = (unsigned short*)alloc(ND * 2);
  unsigned short* qlo    = (unsigned short*)alloc(ND * 2);
  unsigned short* khi    = (unsigned short*)alloc(ND * 2);   // aliased by attnbf
  unsigned short* klo    = (unsigned short*)alloc(ND * 2);
  unsigned short* vtbuf  = (unsigned short*)alloc(ND * 2);
  float*          qnorms = (float*)alloc((size_t)64 * LL * 4);
  float*          knorms = (float*)alloc((size_t)64 * LL * 4);
  float*          pksum  = (float*)alloc((size_t)NSPLIT * 64 * MMF * 4);
  unsigned short* kvT    = (unsigned short*)alloc((size_t)64 * DK * MMF * 2);
  float*          ksg    = (float*)alloc((size_t)64 * MMF * 4);
  float*          pkv    = (float*)xbf;            // 33.5 MB, exact alias
  unsigned short* attnbf = khi;                    // khi dead after kv_mfma

  cvt_bf16<<<16384, 256, 0, stream>>>(x, xbf, (int)ND);
  cvt_bf16_w<<<dim3(1024, 4), 256, 0, stream>>>(Wq, Wk, Wv, Wo,
                                                wqbf, wkbf, wvbf, wobf);
  cvt_orf<<<64, 256, 0, stream>>>(orf, orfhi, orflo, MMF * DK);

  dim3 gg(128, 8);
  gemm_mfma<2><<<gg, 256, 0, stream>>>(xbf, wqbf, bq, (float*)0, qhi, qlo,
                                       qnorms, BB * LL, DD, DD);
  gemm_mfma<2><<<gg, 256, 0, stream>>>(xbf, wkbf, bk, (float*)0, khi, klo,
                                       knorms, BB * LL, DD, DD);
  gemm_mfma<1><<<gg, 256, 0, stream>>>(xbf, wvbf, bv, (float*)0, vtbuf,
                                       (unsigned short*)0, (float*)0,
                                       BB * LL, DD, DD);

  kv_mfma<<<dim3(64, NSPLIT), 512, 0, stream>>>(khi, klo, knorms, vtbuf,
                                                orfhi, orflo, pkv, pksum);
  reduce_parts<<<1024, 256, 0, stream>>>(pkv, kvT, pksum, ksg);
  qattn_mfma<<<dim3(64, 32), 512, 0, stream>>>(qhi, qlo, qnorms, orfhi,
                                               kvT, ksg, attnbf);

  gemm_mfma<0><<<gg, 256, 0, stream>>>(attnbf, wobf, bo, out, (unsigned short*)0,
                                       (unsigned short*)0, (float*)0,
                                       BB * LL, DD, DD);
}

// Round 11
// 298.351 us; speedup vs baseline: 1.1036x; 1.1036x over previous
//
#include <hip/hip_runtime.h>
#include <math.h>

// Problem constants
#define HH 16
#define BB 4
#define LL 4096
#define DD 1024
#define DK 64
#define MMF 256
#define EPSF 1e-6f
// orf scale: 64^-0.25 * log2(e)  (phi computed as exp2)
#define KSCALE (0.35355339059327373f * 1.4426950408889634f)
// norm scale: 1/(2*sqrt(64)) * log2(e)
#define NORMSCALE (0.0625f * 1.4426950408889634f)
#define NSPLIT 8
#define LCH (LL / NSPLIT)             // 512 rows of L per kv block

typedef __attribute__((ext_vector_type(8))) short bf16x8;
typedef __attribute__((ext_vector_type(4))) float f32x4;
typedef __attribute__((ext_vector_type(8))) unsigned short u16x8;

__device__ __forceinline__ unsigned short f2bf(float f) {
  union { float f; unsigned u; } v; v.f = f;
  unsigned r = v.u + 0x7FFF + ((v.u >> 16) & 1);   // RNE
  return (unsigned short)(r >> 16);
}
__device__ __forceinline__ float bf2f(unsigned short h) {
  union { unsigned u; float f; } v; v.u = ((unsigned)h) << 16;
  return v.f;
}
__device__ __forceinline__ f32x4 mfma16(bf16x8 a, bf16x8 b, f32x4 c) {
  return __builtin_amdgcn_mfma_f32_16x16x32_bf16(a, b, c, 0, 0, 0);
}
// single v_exp_f32 (exp2f routes through OCML's precise multi-inst path)
__device__ __forceinline__ float fexp2(float x) {
  return __builtin_amdgcn_exp2f(x);
}
// async global->LDS, 16B per lane; dst is wave-uniform base (lane x16 implicit)
__device__ __forceinline__ void gload16(const unsigned short* g, unsigned short* l) {
  __builtin_amdgcn_global_load_lds(
      (const __attribute__((address_space(1))) void*)g,
      (__attribute__((address_space(3))) void*)l, 16, 0, 0);
}
// T2 swizzle for 64-element bf16 rows (element-index xor)
#define SWZ(row, col) ((col) ^ (((row) & 7) << 3))

// ---------------------------------------------------------------------------
// fp32 -> bf16 conversion (n multiple of 4)
// ---------------------------------------------------------------------------
__global__ __launch_bounds__(256) void cvt_bf16(
    const float* __restrict__ src, unsigned short* __restrict__ dst, int n) {
  int i = (blockIdx.x * 256 + threadIdx.x) * 4;
  if (i < n) {
    float4 v = *(const float4*)&src[i];
    ushort4 o;
    o.x = f2bf(v.x); o.y = f2bf(v.y); o.z = f2bf(v.z); o.w = f2bf(v.w);
    *(ushort4*)&dst[i] = o;
  }
}

// fused 4-way weight conversion, grid (1024, 4)
__global__ __launch_bounds__(256) void cvt_bf16_w(
    const float* __restrict__ W0, const float* __restrict__ W1,
    const float* __restrict__ W2, const float* __restrict__ W3,
    unsigned short* __restrict__ D0, unsigned short* __restrict__ D1,
    unsigned short* __restrict__ D2, unsigned short* __restrict__ D3) {
  const float* s;
  unsigned short* d;
  switch (blockIdx.y) {
    case 0: s = W0; d = D0; break;
    case 1: s = W1; d = D1; break;
    case 2: s = W2; d = D2; break;
    default: s = W3; d = D3; break;
  }
  int i = (blockIdx.x * 256 + threadIdx.x) * 4;
  float4 v = *(const float4*)&s[i];
  ushort4 o;
  o.x = f2bf(v.x); o.y = f2bf(v.y); o.z = f2bf(v.z); o.w = f2bf(v.w);
  *(ushort4*)&d[i] = o;
}

// orf: scale by KSCALE (dk^-.25 * log2e), bf16 (hi only; lo terms retired)
__global__ __launch_bounds__(256) void cvt_orf(
    const float* __restrict__ src, unsigned short* __restrict__ hi, int n) {
  int i = blockIdx.x * 256 + threadIdx.x;
  if (i < n) hi[i] = f2bf(src[i] * KSCALE);
}

// ---------------------------------------------------------------------------
// bf16 MFMA GEMM: C = A[M,K] @ W[N,K]^T + bias. 128x128 tile, BK=64, 4 waves.
// DOUBLE-BUFFERED LDS + counted vmcnt: next tile's 8 global_load_lds stay in
// flight across the compute phase (raw s_barrier; no vmcnt(0) drain in loop).
// Fixed shape M=16384, N=1024 -> grid 128x8, XCD-swizzled.
// Epilogue: per-wave LDS-transpose -> fully coalesced 16B vector stores.
// MODE 0: fp32 C row-major.
// MODE 1: bf16 transposed Ct[(b*16+h)*64+d][4096]                  (V path)
// MODE 2: hi/lo bf16 [bh][l][64] + norms[bh][l] (pre *log2e/16)    (Q,K paths)
// ---------------------------------------------------------------------------
template <int MODE>
__global__ __launch_bounds__(256) void gemm_mfma(
    const unsigned short* __restrict__ A, const unsigned short* __restrict__ W,
    const float* __restrict__ bias, float* __restrict__ Cf,
    unsigned short* __restrict__ C1, unsigned short* __restrict__ C2,
    float* __restrict__ Cn, int M, int N, int K) {
  // [A0 16KB | B0 16KB | A1 16KB | B1 16KB]; epilogue reuses front 34816 B
  __shared__ __align__(16) char smem[65536];
  unsigned short* S = (unsigned short*)smem;
  const int tid = threadIdx.x, lane = tid & 63;
  const int w = tid >> 6, wr = w >> 1, wc = w & 1;
  const int g = lane >> 4, li = lane & 15;
  // XCD swizzle: each XCD owns 16 contiguous M-panels x all 8 N-panels
  const int flat = blockIdx.y * gridDim.x + blockIdx.x;     // 0..1023
  const int xcd = flat & 7, loc = flat >> 3;
  const int m0 = ((xcd << 4) + (loc & 15)) * 128;
  const int n0 = (loc >> 4) * 128;

  f32x4 acc[4][4] = {};
  const int srow8 = lane >> 3;                    // row within 8-row group
  const int scol  = ((lane & 7) ^ srow8) << 3;    // pre-swizzled element col
  const unsigned short* Ag = A + (size_t)(m0 + w * 32 + srow8) * K + scol;
  const unsigned short* Wg = W + (size_t)(n0 + w * 32 + srow8) * K + scol;
  const int nt = K >> 6;

  // prologue: stage tile 0 into buffer 0
#pragma unroll
  for (int j = 0; j < 4; ++j) {
    gload16(Ag + (size_t)j * 8 * K, S + (w * 32 + j * 8) * 64);
    gload16(Wg + (size_t)j * 8 * K, S + 8192 + (w * 32 + j * 8) * 64);
  }

  for (int t = 0; t < nt; ++t) {
    const int co = (t & 1) << 14;           // current buffer (ushort offset)
    const int no = co ^ 16384;              // next buffer
    if (t + 1 < nt) {
      const int k1 = (t + 1) << 6;
#pragma unroll
      for (int j = 0; j < 4; ++j) {
        gload16(Ag + (size_t)j * 8 * K + k1, S + no + (w * 32 + j * 8) * 64);
        gload16(Wg + (size_t)j * 8 * K + k1, S + no + 8192 + (w * 32 + j * 8) * 64);
      }
      // wait only for the CURRENT tile's 8 loads; next 8 stay in flight
      asm volatile("s_waitcnt vmcnt(8)" ::: "memory");
    } else {
      asm volatile("s_waitcnt vmcnt(0)" ::: "memory");
    }
    __builtin_amdgcn_s_barrier();

    const int sx = (li & 7) << 3;
#pragma unroll
    for (int kk = 0; kk < 2; ++kk) {
      const int c = (kk * 32 + g * 8) ^ sx;
      bf16x8 af[4], bfr[4];
#pragma unroll
      for (int i = 0; i < 4; ++i)
        af[i] = *(const bf16x8*)&S[co + (wr * 64 + i * 16 + li) * 64 + c];
#pragma unroll
      for (int j = 0; j < 4; ++j)
        bfr[j] = *(const bf16x8*)&S[co + 8192 + (wc * 64 + j * 16 + li) * 64 + c];
#pragma unroll
      for (int i = 0; i < 4; ++i)
#pragma unroll
        for (int j = 0; j < 4; ++j)
          acc[i][j] = mfma16(af[i], bfr[j], acc[i][j]);
    }
    // ds_reads must COMPLETE before next iteration re-stages this buffer
    asm volatile("s_waitcnt lgkmcnt(0)" ::: "memory");
    __builtin_amdgcn_s_barrier();
  }

  // ---------------- epilogue: LDS transpose, coalesced stores ---------------
  float* ep = (float*)smem + w * (32 * 68);
  const int head = (n0 + wc * 64) >> 6;
  const int rbase = m0 + wr * 64;       // global row base of this wave's tile
  const int b = rbase >> 12;            // batch (tile never crosses b boundary)

  if (MODE == 2) {
#pragma unroll
    for (int jh = 0; jh < 2; ++jh) {
      // write half: local rows 0..31 = global rows jh*32..+31, all 64 cols
#pragma unroll
      for (int i2 = 0; i2 < 2; ++i2) {
        const int i = jh * 2 + i2;
#pragma unroll
        for (int j = 0; j < 4; ++j) {
          const float bz = bias[n0 + wc * 64 + j * 16 + li];
#pragma unroll
          for (int r = 0; r < 4; ++r)
            ep[(i2 * 16 + 4 * g + r) * 68 + j * 16 + li] = acc[i][j][r] + bz;
        }
      }
      // read half: lane -> (row = p*8 + lane>>3, chunk c = lane&7 of 8 f32)
      const int rrow = lane >> 3, cc = lane & 7;
#pragma unroll
      for (int p = 0; p < 4; ++p) {
        const int row = p * 8 + rrow;
        float v[8];
        *(f32x4*)&v[0] = *(const f32x4*)&ep[row * 68 + cc * 8];
        *(f32x4*)&v[4] = *(const f32x4*)&ep[row * 68 + cc * 8 + 4];
        float np = 0.f;
        u16x8 hv, lv;
#pragma unroll
        for (int e = 0; e < 8; ++e) {
          float vv = v[e];
          np += vv * vv;
          unsigned short h = f2bf(vv);
          hv[e] = h;
          lv[e] = f2bf(vv - bf2f(h));
        }
        const int lg = (rbase + jh * 32 + row) & 4095;
        const size_t rowb = (size_t)(b * 16 + head) * 4096 + lg;
        *(u16x8*)&C1[rowb * 64 + cc * 8] = hv;
        *(u16x8*)&C2[rowb * 64 + cc * 8] = lv;
        np += __shfl_xor(np, 1);
        np += __shfl_xor(np, 2);
        np += __shfl_xor(np, 4);
        if (cc == 0) Cn[rowb] = np * NORMSCALE;
      }
    }
  } else if (MODE == 1) {
#pragma unroll
    for (int jh = 0; jh < 2; ++jh) {
      // write half: LDS [32 d][68 l]; acc's 4 rows (l) contiguous -> b128
#pragma unroll
      for (int i = 0; i < 4; ++i)
#pragma unroll
        for (int j2 = 0; j2 < 2; ++j2) {
          const int j = jh * 2 + j2;
          const float bz = bias[n0 + wc * 64 + j * 16 + li];
          f32x4 t;
          t[0] = acc[i][j][0] + bz; t[1] = acc[i][j][1] + bz;
          t[2] = acc[i][j][2] + bz; t[3] = acc[i][j][3] + bz;
          *(f32x4*)&ep[(j2 * 16 + li) * 68 + i * 16 + 4 * g] = t;
        }
      // read half: lane -> (d = p*8 + lane>>3, chunk c = lane&7 of 8 l)
      const int rd = lane >> 3, cc = lane & 7;
#pragma unroll
      for (int p = 0; p < 4; ++p) {
        const int dl = p * 8 + rd;
        float v[8];
        *(f32x4*)&v[0] = *(const f32x4*)&ep[dl * 68 + cc * 8];
        *(f32x4*)&v[4] = *(const f32x4*)&ep[dl * 68 + cc * 8 + 4];
        u16x8 hv;
#pragma unroll
        for (int e = 0; e < 8; ++e) hv[e] = f2bf(v[e]);
        const int dh = jh * 32 + dl;
        const int lg = rbase & 4095;
        *(u16x8*)&C1[((size_t)(b * 16 + head) * 64 + dh) * 4096 + lg + cc * 8] = hv;
      }
    }
  } else {  // MODE 0: fp32 row-major
#pragma unroll
    for (int jh = 0; jh < 2; ++jh) {
#pragma unroll
      for (int i2 = 0; i2 < 2; ++i2) {
        const int i = jh * 2 + i2;
#pragma unroll
        for (int j = 0; j < 4; ++j) {
          const float bz = bias[n0 + wc * 64 + j * 16 + li];
#pragma unroll
          for (int r = 0; r < 4; ++r)
            ep[(i2 * 16 + 4 * g + r) * 68 + j * 16 + li] = acc[i][j][r] + bz;
        }
      }
      // read: lane -> (row = p*4 + lane>>4, chunk c = lane&15 of 4 f32)
      const int rrow = lane >> 4, cc = lane & 15;
#pragma unroll
      for (int p = 0; p < 8; ++p) {
        const int row = p * 4 + rrow;
        f32x4 v = *(const f32x4*)&ep[row * 68 + cc * 4];
        *(f32x4*)&Cf[(size_t)(rbase + jh * 32 + row) * 1024 + n0 + wc * 64 + cc * 4] = v;
      }
    }
  }
}

// ---------------------------------------------------------------------------
// kv + ksum. grid (64 bh, NSPLIT), 256 thr / 4 waves (r7 structure — best of
// r7/r9/r10). 2-TERM proj split: oh·(khi + klo) — orf-lo retired (mirrors
// qattn's r5 change, absmax-neutral). phi via single v_exp_f32.
// ---------------------------------------------------------------------------
__global__ __launch_bounds__(256, 2) void kv_mfma(
    const unsigned short* __restrict__ khi, const unsigned short* __restrict__ klo,
    const float* __restrict__ knorms, const unsigned short* __restrict__ vt,
    const unsigned short* __restrict__ orfhi,
    float* __restrict__ pkv, float* __restrict__ pksum) {
  __shared__ __align__(16) unsigned short KsHi[64 * 64], KsLo[64 * 64];
  __shared__ __align__(16) unsigned short VT[64 * 64], KphiT[64 * 64];
  __shared__ float ns[64];
  const int tid = threadIdx.x, lane = tid & 63, w = tid >> 6;
  const int g = lane >> 4, li = lane & 15;
  const int bh = blockIdx.x, sp = blockIdx.y;
  const int srow8 = lane >> 3;
  const int scol  = ((lane & 7) ^ srow8) << 3;
  const int sx = (li & 7) << 3;

  // orf-hi fragments in registers: A-operand rows m = p*64 + w*16 + li
  bf16x8 oh[4][2];
#pragma unroll
  for (int p = 0; p < 4; ++p)
#pragma unroll
    for (int kk = 0; kk < 2; ++kk)
      oh[p][kk] = *(const bf16x8*)
          &orfhi[(size_t)(p * 64 + w * 16 + li) * 64 + kk * 32 + g * 8];

  f32x4 kvacc[4][4] = {};
  float ksacc[4][4] = {};

  for (int c = 0; c < LCH / 64; ++c) {
    const int l0 = sp * LCH + c * 64;
    __syncthreads();   // previous chunk's readers done
    {  // stage K hi/lo + V^T via gload (pre-swizzled source, linear LDS)
      const size_t kb = ((size_t)bh * 4096 + l0 + w * 16 + srow8) * 64 + scol;
      gload16(khi + kb, &KsHi[(w * 16) * 64]);
      gload16(khi + kb + 8 * 64, &KsHi[(w * 16 + 8) * 64]);
      gload16(klo + kb, &KsLo[(w * 16) * 64]);
      gload16(klo + kb + 8 * 64, &KsLo[(w * 16 + 8) * 64]);
      const size_t vb = ((size_t)bh * 64 + w * 16 + srow8) * 4096 + l0 + scol;
      gload16(vt + vb, &VT[(w * 16) * 64]);
      gload16(vt + vb + (size_t)8 * 4096, &VT[(w * 16 + 8) * 64]);
      if (tid < 64) ns[tid] = knorms[(size_t)bh * 4096 + l0 + tid];
    }
    __syncthreads();

#pragma unroll
    for (int p = 0; p < 4; ++p) {
      // projT[m][l], 2-term: oh*khi + oh*klo
      f32x4 pr[4] = {};
      __builtin_amdgcn_s_setprio(1);
#pragma unroll
      for (int kk = 0; kk < 2; ++kk) {
        const int cx = (kk * 32 + g * 8) ^ sx;
#pragma unroll
        for (int lf = 0; lf < 4; ++lf) {
          const bf16x8 bh2 = *(const bf16x8*)&KsHi[(lf * 16 + li) * 64 + cx];
          const bf16x8 bl2 = *(const bf16x8*)&KsLo[(lf * 16 + li) * 64 + cx];
          pr[lf] = mfma16(oh[p][kk], bh2, pr[lf]);
          pr[lf] = mfma16(oh[p][kk], bl2, pr[lf]);
        }
      }
      __builtin_amdgcn_s_setprio(0);
      // phi (v_exp_f32) + ksum + KphiT (wave-private rows, swizzled)
#pragma unroll
      for (int lf = 0; lf < 4; ++lf) {
        const float nrm = ns[lf * 16 + li];
#pragma unroll
        for (int r = 0; r < 4; ++r) {
          float phi = fexp2(pr[lf][r] - nrm) + EPSF;
          ksacc[p][r] += phi;
          const int row = w * 16 + 4 * g + r;
          KphiT[row * 64 + SWZ(row, lf * 16 + li)] = f2bf(phi);
        }
      }
      // kv += KphiT . V^T (same-wave LDS dependence, no barrier)
      __builtin_amdgcn_s_setprio(1);
#pragma unroll
      for (int kk = 0; kk < 2; ++kk) {
        const int cx = (kk * 32 + g * 8) ^ sx;
        const bf16x8 a = *(const bf16x8*)&KphiT[(w * 16 + li) * 64 + cx];
#pragma unroll
        for (int df = 0; df < 4; ++df) {
          const bf16x8 bv = *(const bf16x8*)&VT[(df * 16 + li) * 64 + cx];
          kvacc[p][df] = mfma16(a, bv, kvacc[p][df]);
        }
      }
      __builtin_amdgcn_s_setprio(0);
    }
  }
  float* kvo = pkv + ((size_t)sp * 64 + bh) * (MMF * DK);
#pragma unroll
  for (int p = 0; p < 4; ++p)
#pragma unroll
    for (int df = 0; df < 4; ++df)
#pragma unroll
      for (int r = 0; r < 4; ++r)
        kvo[(p * 64 + w * 16 + 4 * g + r) * DK + df * 16 + li] = kvacc[p][df][r];

  float* kso = pksum + ((size_t)sp * 64 + bh) * MMF;
#pragma unroll
  for (int p = 0; p < 4; ++p)
#pragma unroll
    for (int r = 0; r < 4; ++r) {
      float s = ksacc[p][r];
      s += __shfl_xor(s, 1); s += __shfl_xor(s, 2);
      s += __shfl_xor(s, 4); s += __shfl_xor(s, 8);
      if (li == 0) kso[p * 64 + w * 16 + 4 * g + r] = s;
    }
}

// ---------------------------------------------------------------------------
// reduce partials; emit kv TRANSPOSED bf16 kvT[bh][d][m] + ksum fp32
// ---------------------------------------------------------------------------
__global__ __launch_bounds__(256) void reduce_parts(
    const float* __restrict__ pkv, unsigned short* __restrict__ kvT,
    const float* __restrict__ pks, float* __restrict__ ksg) {
  const int id = blockIdx.x * 256 + threadIdx.x;   // grid 1024 -> 262144
  {
    const int bh = id >> 12, rest = id & 4095;
    const int m0 = (rest >> 6) << 2, d = rest & 63;
    float s0 = 0.f, s1 = 0.f, s2 = 0.f, s3 = 0.f;
#pragma unroll
    for (int sp = 0; sp < NSPLIT; ++sp) {
      const float* p = pkv + (size_t)(sp * 64 + bh) * (MMF * DK) + d;
      s0 += p[(m0 + 0) * DK]; s1 += p[(m0 + 1) * DK];
      s2 += p[(m0 + 2) * DK]; s3 += p[(m0 + 3) * DK];
    }
    ushort4 o;
    o.x = f2bf(s0); o.y = f2bf(s1); o.z = f2bf(s2); o.w = f2bf(s3);
    *(ushort4*)&kvT[((size_t)bh * DK + d) * MMF + m0] = o;
  }
  if (id < 4096) {
    float4 s = {0.f, 0.f, 0.f, 0.f};
#pragma unroll
    for (int sp = 0; sp < NSPLIT; ++sp) {
      float4 v = *(const float4*)&pks[(size_t)sp * 64 * MMF + id * 4];
      s.x += v.x; s.y += v.y; s.z += v.z; s.w += v.w;
    }
    *(float4*)&ksg[id * 4] = s;
  }
}

// ---------------------------------------------------------------------------
// q_phi + num/den -> attn (bf16). grid (64 bh, 32 l-blocks), 512 threads.
// 2-term proj split. Q frags / norms / ksums in registers; OHi + kvT resident
// in LDS (80KB -> 2 blocks/CU); barrier-free loop; phi via single v_exp_f32.
// ---------------------------------------------------------------------------
__global__ __launch_bounds__(512, 4) void qattn_mfma(
    const unsigned short* __restrict__ qhi, const unsigned short* __restrict__ qlo,
    const float* __restrict__ qnorms,
    const unsigned short* __restrict__ orfhi,
    const unsigned short* __restrict__ kvT, const float* __restrict__ ksg,
    unsigned short* __restrict__ attn) {
  __shared__ __align__(16) unsigned short OHi[256 * 64];    // 32 KB
  __shared__ __align__(16) unsigned short KvTs[64 * 256];   // 32 KB
  __shared__ __align__(16) unsigned short Qphi[8][16 * 64]; // 16 KB  -> 80 KB total
  const int tid = threadIdx.x, lane = tid & 63, w = tid >> 6;   // w: 0..7
  const int g = lane >> 4, li = lane & 15;
  const int bh = blockIdx.x, lb = blockIdx.y;
  const int b = bh >> 4, h = bh & 15;
  const int srow8 = lane >> 3;
  const int scol  = ((lane & 7) ^ srow8) << 3;
  const int sx = (li & 7) << 3;

  // ---- one-time staging ----
#pragma unroll
  for (int q = 0; q < 4; ++q) {   // orf-hi: wave w stages rows w*32 .. w*32+31
    const size_t o = (size_t)(w * 32 + q * 8 + srow8) * 64 + scol;
    gload16(orfhi + o, &OHi[(w * 32 + q * 8) * 64]);
  }
  {  // kvT: 64 rows x 512B; 2 rows per gload; wave w stages rows w*8..w*8+7
    const int srow2 = lane >> 5;                  // 0..1
#pragma unroll
    for (int q = 0; q < 4; ++q) {
      const int d0 = w * 8 + q * 2, dr = d0 + srow2;
      gload16(kvT + ((size_t)bh * DK + dr) * MMF + (((lane & 31) ^ (dr & 7)) << 3),
              &KvTs[d0 * 256]);
    }
  }

  // registers: ksums, norms, Q fragments
  float ksr[4][4];
#pragma unroll
  for (int p = 0; p < 4; ++p)
#pragma unroll
    for (int mf = 0; mf < 4; ++mf)
      ksr[p][mf] = ksg[(size_t)bh * MMF + p * 64 + mf * 16 + li];
  const float4 nr =
      *(const float4*)&qnorms[(size_t)bh * 4096 + lb * 128 + w * 16 + 4 * g];
  bf16x8 qh[2], ql[2];
  {
    const size_t qr = ((size_t)bh * 4096 + lb * 128 + w * 16 + li) * 64 + g * 8;
    qh[0] = *(const bf16x8*)&qhi[qr];
    qh[1] = *(const bf16x8*)&qhi[qr + 32];
    ql[0] = *(const bf16x8*)&qlo[qr];
    ql[1] = *(const bf16x8*)&qlo[qr + 32];
  }
  __syncthreads();   // gload staging complete

  f32x4 numacc[4] = {};
  float denacc[4] = {};

#pragma unroll
  for (int p = 0; p < 4; ++p) {
    // proj[l][m], 2-term split (qh*oh + ql*oh)
    f32x4 pr[4] = {};
    __builtin_amdgcn_s_setprio(1);
#pragma unroll
    for (int kk = 0; kk < 2; ++kk) {
      const int cx = (kk * 32 + g * 8) ^ sx;
#pragma unroll
      for (int mf = 0; mf < 4; ++mf) {
        const int row = p * 64 + mf * 16 + li;
        const bf16x8 bh2 = *(const bf16x8*)&OHi[row * 64 + cx];
        pr[mf] = mfma16(qh[kk], bh2, pr[mf]);
        pr[mf] = mfma16(ql[kk], bh2, pr[mf]);
      }
    }
    __builtin_amdgcn_s_setprio(0);
    // phi (v_exp_f32), den partial, Qphi (wave-private, swizzled)
#pragma unroll
    for (int mf = 0; mf < 4; ++mf) {
      const float ks = ksr[p][mf];
#pragma unroll
      for (int r = 0; r < 4; ++r) {
        float phi = fexp2(pr[mf][r] - nr[r]) + EPSF;
        denacc[r] += phi * ks;
        const int row = 4 * g + r;
        Qphi[w][row * 64 + SWZ(row, mf * 16 + li)] = f2bf(phi);
      }
    }
    // num += Qphi . kvT (same-wave Qphi; KvTs stable)
    __builtin_amdgcn_s_setprio(1);
#pragma unroll
    for (int kk = 0; kk < 2; ++kk) {
      const int cx = (kk * 32 + g * 8) ^ sx;
      const bf16x8 a = *(const bf16x8*)&Qphi[w][li * 64 + cx];
#pragma unroll
      for (int df = 0; df < 4; ++df) {
        const bf16x8 bv = *(const bf16x8*)
            &KvTs[(df * 16 + li) * 256 + (((p * 8 + kk * 4 + g) ^ (li & 7)) << 3)];
        numacc[df] = mfma16(a, bv, numacc[df]);
      }
    }
    __builtin_amdgcn_s_setprio(0);
  }
  float den[4];
#pragma unroll
  for (int r = 0; r < 4; ++r) {
    float s = denacc[r];
    s += __shfl_xor(s, 1); s += __shfl_xor(s, 2);
    s += __shfl_xor(s, 4); s += __shfl_xor(s, 8);
    den[r] = s;
  }
  unsigned short* ab =
      attn + ((size_t)b * 4096 + lb * 128) * 1024 + h * 64;
#pragma unroll
  for (int df = 0; df < 4; ++df)
#pragma unroll
    for (int r = 0; r < 4; ++r)
      ab[(size_t)(w * 16 + 4 * g + r) * 1024 + df * 16 + li] =
          f2bf(numacc[df][r] / den[r]);
}

// ---------------------------------------------------------------------------
extern "C" void kernel_launch(void* const* d_in, const int* in_sizes, int n_in,
                              void* d_out, int out_size, void* d_ws, size_t ws_size,
                              hipStream_t stream) {
  (void)in_sizes; (void)n_in; (void)out_size; (void)ws_size;
  const float* x   = (const float*)d_in[0];
  const float* Wq  = (const float*)d_in[1];
  const float* bq  = (const float*)d_in[2];
  const float* Wk  = (const float*)d_in[3];
  const float* bk  = (const float*)d_in[4];
  const float* Wv  = (const float*)d_in[5];
  const float* bv  = (const float*)d_in[6];
  const float* Wo  = (const float*)d_in[7];
  const float* bo  = (const float*)d_in[8];
  const float* orf = (const float*)d_in[9];
  float* out = (float*)d_out;

  const size_t ND = (size_t)BB * LL * DD;   // 16,777,216
  char* base = (char*)d_ws;
  size_t off = 0;
  auto alloc = [&](size_t bytes) -> char* {
    char* p = base + off;
    off += (bytes + 255) & ~(size_t)255;
    return p;
  };
  unsigned short* wqbf   = (unsigned short*)alloc((size_t)DD * DD * 2);
  unsigned short* wkbf   = (unsigned short*)alloc((size_t)DD * DD * 2);
  unsigned short* wvbf   = (unsigned short*)alloc((size_t)DD * DD * 2);
  unsigned short* wobf   = (unsigned short*)alloc((size_t)DD * DD * 2);
  unsigned short* orfhi  = (unsigned short*)alloc((size_t)MMF * DK * 2);
  unsigned short* xbf    = (unsigned short*)alloc(ND * 2);   // aliased by pkv
  unsigned short* qhi    = (unsigned short*)alloc(ND * 2);
  unsigned short* qlo    = (unsigned short*)alloc(ND * 2);
  unsigned short* khi    = (unsigned short*)alloc(ND * 2);   // aliased by attnbf
  unsigned short* klo    = (unsigned short*)alloc(ND * 2);
  unsigned short* vtbuf  = (unsigned short*)alloc(ND * 2);
  float*          qnorms = (float*)alloc((size_t)64 * LL * 4);
  float*          knorms = (float*)alloc((size_t)64 * LL * 4);
  float*          pksum  = (float*)alloc((size_t)NSPLIT * 64 * MMF * 4);
  unsigned short* kvT    = (unsigned short*)alloc((size_t)64 * DK * MMF * 2);
  float*          ksg    = (float*)alloc((size_t)64 * MMF * 4);
  float*          pkv    = (float*)xbf;            // 33.5 MB, exact alias
  unsigned short* attnbf = khi;                    // khi dead after kv_mfma

  cvt_bf16<<<16384, 256, 0, stream>>>(x, xbf, (int)ND);
  cvt_bf16_w<<<dim3(1024, 4), 256, 0, stream>>>(Wq, Wk, Wv, Wo,
                                                wqbf, wkbf, wvbf, wobf);
  cvt_orf<<<64, 256, 0, stream>>>(orf, orfhi, MMF * DK);

  dim3 gg(128, 8);
  gemm_mfma<2><<<gg, 256, 0, stream>>>(xbf, wqbf, bq, (float*)0, qhi, qlo,
                                       qnorms, BB * LL, DD, DD);
  gemm_mfma<2><<<gg, 256, 0, stream>>>(xbf, wkbf, bk, (float*)0, khi, klo,
                                       knorms, BB * LL, DD, DD);
  gemm_mfma<1><<<gg, 256, 0, stream>>>(xbf, wvbf, bv, (float*)0, vtbuf,
                                       (unsigned short*)0, (float*)0,
                                       BB * LL, DD, DD);

  kv_mfma<<<dim3(64, NSPLIT), 256, 0, stream>>>(khi, klo, knorms, vtbuf,
                                                orfhi, pkv, pksum);
  reduce_parts<<<1024, 256, 0, stream>>>(pkv, kvT, pksum, ksg);
  qattn_mfma<<<dim3(64, 32), 512, 0, stream>>>(qhi, qlo, qnorms, orfhi,
                                               kvT, ksg, attnbf);

  gemm_mfma<0><<<gg, 256, 0, stream>>>(attnbf, wobf, bo, out, (unsigned short*)0,
                                       (unsigned short*)0, (float*)0,
                                       BB * LL, DD, DD);
}

// Round 12
// 286.496 us; speedup vs baseline: 1.1493x; 1.0414x over previous
//
#include <hip/hip_runtime.h>
#include <math.h>

// Problem constants
#define HH 16
#define BB 4
#define LL 4096
#define DD 1024
#define DK 64
#define MMF 256
#define EPSF 1e-6f
// orf scale: 64^-0.25 * log2(e)  (phi computed as exp2)
#define KSCALE (0.35355339059327373f * 1.4426950408889634f)
// norm scale: 1/(2*sqrt(64)) * log2(e)
#define NORMSCALE (0.0625f * 1.4426950408889634f)
#define NSPLIT 8
#define LCH (LL / NSPLIT)             // 512 rows of L per kv block

typedef __attribute__((ext_vector_type(8))) short bf16x8;
typedef __attribute__((ext_vector_type(4))) float f32x4;
typedef __attribute__((ext_vector_type(8))) unsigned short u16x8;

__device__ __forceinline__ unsigned short f2bf(float f) {
  union { float f; unsigned u; } v; v.f = f;
  unsigned r = v.u + 0x7FFF + ((v.u >> 16) & 1);   // RNE
  return (unsigned short)(r >> 16);
}
__device__ __forceinline__ float bf2f(unsigned short h) {
  union { unsigned u; float f; } v; v.u = ((unsigned)h) << 16;
  return v.f;
}
__device__ __forceinline__ f32x4 mfma16(bf16x8 a, bf16x8 b, f32x4 c) {
  return __builtin_amdgcn_mfma_f32_16x16x32_bf16(a, b, c, 0, 0, 0);
}
// single v_exp_f32 (exp2f routes through OCML's precise multi-inst path)
__device__ __forceinline__ float fexp2(float x) {
  return __builtin_amdgcn_exp2f(x);
}
// async global->LDS, 16B per lane; dst is wave-uniform base (lane x16 implicit)
__device__ __forceinline__ void gload16(const unsigned short* g, unsigned short* l) {
  __builtin_amdgcn_global_load_lds(
      (const __attribute__((address_space(1))) void*)g,
      (__attribute__((address_space(3))) void*)l, 16, 0, 0);
}
// T2 swizzle for 64-element bf16 rows (element-index xor)
#define SWZ(row, col) ((col) ^ (((row) & 7) << 3))

// ---------------------------------------------------------------------------
// fp32 -> bf16 conversion (n multiple of 4)
// ---------------------------------------------------------------------------
__global__ __launch_bounds__(256) void cvt_bf16(
    const float* __restrict__ src, unsigned short* __restrict__ dst, int n) {
  int i = (blockIdx.x * 256 + threadIdx.x) * 4;
  if (i < n) {
    float4 v = *(const float4*)&src[i];
    ushort4 o;
    o.x = f2bf(v.x); o.y = f2bf(v.y); o.z = f2bf(v.z); o.w = f2bf(v.w);
    *(ushort4*)&dst[i] = o;
  }
}

// fused 4-way weight conversion, grid (1024, 4)
__global__ __launch_bounds__(256) void cvt_bf16_w(
    const float* __restrict__ W0, const float* __restrict__ W1,
    const float* __restrict__ W2, const float* __restrict__ W3,
    unsigned short* __restrict__ D0, unsigned short* __restrict__ D1,
    unsigned short* __restrict__ D2, unsigned short* __restrict__ D3) {
  const float* s;
  unsigned short* d;
  switch (blockIdx.y) {
    case 0: s = W0; d = D0; break;
    case 1: s = W1; d = D1; break;
    case 2: s = W2; d = D2; break;
    default: s = W3; d = D3; break;
  }
  int i = (blockIdx.x * 256 + threadIdx.x) * 4;
  float4 v = *(const float4*)&s[i];
  ushort4 o;
  o.x = f2bf(v.x); o.y = f2bf(v.y); o.z = f2bf(v.z); o.w = f2bf(v.w);
  *(ushort4*)&d[i] = o;
}

// orf: scale by KSCALE (dk^-.25 * log2e), bf16
__global__ __launch_bounds__(256) void cvt_orf(
    const float* __restrict__ src, unsigned short* __restrict__ hi, int n) {
  int i = blockIdx.x * 256 + threadIdx.x;
  if (i < n) hi[i] = f2bf(src[i] * KSCALE);
}

// ---------------------------------------------------------------------------
// bf16 MFMA GEMM, 256x256 tile, BK=64, 8 waves (2Mx4N), wave tile 128x64.
// Double-buffered 128KB LDS; T2 swizzle; all 8 next-tile gload16 issued at
// top of phase 0 (~1.5-phase lead), boundary vmcnt(0) at phase-1 end.
// Grid 64x4 = 256 blocks, bijective XCD swizzle (8 m-panels x 4 n-panels/XCD).
// Epilogue: per-wave LDS-transpose (4 chunks of 32 rows) -> coalesced stores.
// MODE 0: fp32 C row-major.
// MODE 1: bf16 transposed Ct[(b*16+h)*64+d][4096]                  (V path)
// MODE 2: hi/lo bf16 [bh][l][64] + norms[bh][l] (pre *log2e/16)    (Q,K paths)
// ---------------------------------------------------------------------------
template <int MODE>
__global__ __launch_bounds__(512, 2) void gemm_mfma(
    const unsigned short* __restrict__ A, const unsigned short* __restrict__ W,
    const float* __restrict__ bias, float* __restrict__ Cf,
    unsigned short* __restrict__ C1, unsigned short* __restrict__ C2,
    float* __restrict__ Cn, int M, int N, int K) {
  // [A0 32KB | B0 32KB | A1 32KB | B1 32KB]; epilogue reuses front ~70KB
  __shared__ __align__(16) char smem[131072];
  unsigned short* S = (unsigned short*)smem;
  const int tid = threadIdx.x, lane = tid & 63;
  const int w = tid >> 6;                 // 0..7
  const int wm = w >> 2, wn = w & 3;      // 2 M x 4 N waves
  const int g = lane >> 4, li = lane & 15;
  // bijective XCD swizzle: 256 blocks, each XCD: 8 m-panels x 4 n-panels
  const int flat = blockIdx.y * gridDim.x + blockIdx.x;   // 0..255
  const int xcd = flat & 7, loc = flat >> 3;              // loc 0..31
  const int m0 = (xcd * 8 + (loc & 7)) * 256;
  const int n0 = (loc >> 3) * 256;

  f32x4 acc[8][4] = {};
  const int srow8 = lane >> 3;                    // row within 8-row group
  const int scol  = ((lane & 7) ^ srow8) << 3;    // pre-swizzled element col
  const unsigned short* Ast = A + (size_t)(m0 + w * 32 + srow8) * K + scol;
  const unsigned short* Wst = W + (size_t)(n0 + w * 32 + srow8) * K + scol;
  const int nt = K >> 6;
  const int sx = (li & 7) << 3;

  // prologue: stage tile 0 into buffer 0 (A 256x64, B 256x64; 8 gloads/wave)
#pragma unroll
  for (int gi = 0; gi < 4; ++gi) {
    gload16(Ast + (size_t)gi * 8 * K, S + (w * 32 + gi * 8) * 64);
    gload16(Wst + (size_t)gi * 8 * K, S + 16384 + (w * 32 + gi * 8) * 64);
  }
  asm volatile("s_waitcnt vmcnt(0)" ::: "memory");
  __builtin_amdgcn_s_barrier();

  for (int kt = 0; kt < nt; ++kt) {
    const int co = (kt & 1) << 15;          // current buffer (ushort offset)
    const int no = co ^ 32768;              // next buffer
    // ---- phase 0: issue next-tile stages FIRST (max lead), then kk=0 ----
    if (kt + 1 < nt) {
      const size_t k1 = (size_t)(kt + 1) << 6;
#pragma unroll
      for (int gi = 0; gi < 4; ++gi) {
        gload16(Ast + (size_t)gi * 8 * K + k1, S + no + (w * 32 + gi * 8) * 64);
        gload16(Wst + (size_t)gi * 8 * K + k1,
                S + no + 16384 + (w * 32 + gi * 8) * 64);
      }
    }
    {
      const int c = (g * 8) ^ sx;
      bf16x8 af[8], bfr[4];
#pragma unroll
      for (int i = 0; i < 8; ++i)
        af[i] = *(const bf16x8*)&S[co + (wm * 128 + i * 16 + li) * 64 + c];
#pragma unroll
      for (int j = 0; j < 4; ++j)
        bfr[j] = *(const bf16x8*)&S[co + 16384 + (wn * 64 + j * 16 + li) * 64 + c];
      __builtin_amdgcn_s_setprio(1);
#pragma unroll
      for (int i = 0; i < 8; ++i)
#pragma unroll
        for (int j = 0; j < 4; ++j)
          acc[i][j] = mfma16(af[i], bfr[j], acc[i][j]);
      __builtin_amdgcn_s_setprio(0);
    }
    __builtin_amdgcn_s_barrier();
    // ---- phase 1: kk=1 ----
    {
      const int c = (32 + g * 8) ^ sx;
      bf16x8 af[8], bfr[4];
#pragma unroll
      for (int i = 0; i < 8; ++i)
        af[i] = *(const bf16x8*)&S[co + (wm * 128 + i * 16 + li) * 64 + c];
#pragma unroll
      for (int j = 0; j < 4; ++j)
        bfr[j] = *(const bf16x8*)&S[co + 16384 + (wn * 64 + j * 16 + li) * 64 + c];
      __builtin_amdgcn_s_setprio(1);
#pragma unroll
      for (int i = 0; i < 8; ++i)
#pragma unroll
        for (int j = 0; j < 4; ++j)
          acc[i][j] = mfma16(af[i], bfr[j], acc[i][j]);
      __builtin_amdgcn_s_setprio(0);
    }
    if (kt + 1 < nt) asm volatile("s_waitcnt vmcnt(0)" ::: "memory");
    __builtin_amdgcn_s_barrier();
  }

  // ---------------- epilogue: LDS transpose, coalesced stores ---------------
  float* ep = (float*)smem + w * (32 * 68);
  const int head = (n0 + wn * 64) >> 6;
  const int rbase = m0 + wm * 128;      // global row base of this wave's tile
  const int b = rbase >> 12;            // batch (tile never crosses b boundary)

  if (MODE == 2) {
#pragma unroll
    for (int jh = 0; jh < 4; ++jh) {
      // write chunk: local rows 0..31 = wave rows jh*32..+31, all 64 cols
#pragma unroll
      for (int i2 = 0; i2 < 2; ++i2) {
        const int i = jh * 2 + i2;
#pragma unroll
        for (int j = 0; j < 4; ++j) {
          const float bz = bias[n0 + wn * 64 + j * 16 + li];
#pragma unroll
          for (int r = 0; r < 4; ++r)
            ep[(i2 * 16 + 4 * g + r) * 68 + j * 16 + li] = acc[i][j][r] + bz;
        }
      }
      // read chunk: lane -> (row = p*8 + lane>>3, chunk c = lane&7 of 8 f32)
      const int rrow = lane >> 3, cc = lane & 7;
#pragma unroll
      for (int p = 0; p < 4; ++p) {
        const int row = p * 8 + rrow;
        float v[8];
        *(f32x4*)&v[0] = *(const f32x4*)&ep[row * 68 + cc * 8];
        *(f32x4*)&v[4] = *(const f32x4*)&ep[row * 68 + cc * 8 + 4];
        float np = 0.f;
        u16x8 hv, lv;
#pragma unroll
        for (int e = 0; e < 8; ++e) {
          float vv = v[e];
          np += vv * vv;
          unsigned short h = f2bf(vv);
          hv[e] = h;
          lv[e] = f2bf(vv - bf2f(h));
        }
        const int lg = (rbase + jh * 32 + row) & 4095;
        const size_t rowb = (size_t)(b * 16 + head) * 4096 + lg;
        *(u16x8*)&C1[rowb * 64 + cc * 8] = hv;
        *(u16x8*)&C2[rowb * 64 + cc * 8] = lv;
        np += __shfl_xor(np, 1);
        np += __shfl_xor(np, 2);
        np += __shfl_xor(np, 4);
        if (cc == 0) Cn[rowb] = np * NORMSCALE;
      }
      __builtin_amdgcn_s_barrier();
    }
  } else if (MODE == 1) {
#pragma unroll
    for (int jh = 0; jh < 2; ++jh) {        // d-half of the wave's 64 dims
#pragma unroll
      for (int lh = 0; lh < 2; ++lh) {      // l-half of the wave's 128 rows
        // write: LDS [32 d][68 l]
#pragma unroll
        for (int i2 = 0; i2 < 4; ++i2) {
          const int i = lh * 4 + i2;
#pragma unroll
          for (int j2 = 0; j2 < 2; ++j2) {
            const int j = jh * 2 + j2;
            const float bz = bias[n0 + wn * 64 + j * 16 + li];
            f32x4 t;
            t[0] = acc[i][j][0] + bz; t[1] = acc[i][j][1] + bz;
            t[2] = acc[i][j][2] + bz; t[3] = acc[i][j][3] + bz;
            *(f32x4*)&ep[(j2 * 16 + li) * 68 + i2 * 16 + 4 * g] = t;
          }
        }
        // read: lane -> (d = p*8 + lane>>3, chunk c = lane&7 of 8 l)
        const int rd = lane >> 3, cc = lane & 7;
#pragma unroll
        for (int p = 0; p < 4; ++p) {
          const int dl = p * 8 + rd;
          float v[8];
          *(f32x4*)&v[0] = *(const f32x4*)&ep[dl * 68 + cc * 8];
          *(f32x4*)&v[4] = *(const f32x4*)&ep[dl * 68 + cc * 8 + 4];
          u16x8 hv;
#pragma unroll
          for (int e = 0; e < 8; ++e) hv[e] = f2bf(v[e]);
          const int dh = jh * 32 + dl;
          const int lg = (rbase + lh * 64) & 4095;
          *(u16x8*)&C1[((size_t)(b * 16 + head) * 64 + dh) * 4096 + lg + cc * 8] = hv;
        }
        __builtin_amdgcn_s_barrier();
      }
    }
  } else {  // MODE 0: fp32 row-major
#pragma unroll
    for (int jh = 0; jh < 4; ++jh) {
#pragma unroll
      for (int i2 = 0; i2 < 2; ++i2) {
        const int i = jh * 2 + i2;
#pragma unroll
        for (int j = 0; j < 4; ++j) {
          const float bz = bias[n0 + wn * 64 + j * 16 + li];
#pragma unroll
          for (int r = 0; r < 4; ++r)
            ep[(i2 * 16 + 4 * g + r) * 68 + j * 16 + li] = acc[i][j][r] + bz;
        }
      }
      // read: lane -> (row = p*4 + lane>>4, chunk c = lane&15 of 4 f32)
      const int rrow = lane >> 4, cc = lane & 15;
#pragma unroll
      for (int p = 0; p < 8; ++p) {
        const int row = p * 4 + rrow;
        f32x4 v = *(const f32x4*)&ep[row * 68 + cc * 4];
        *(f32x4*)&Cf[(size_t)(rbase + jh * 32 + row) * 1024 + n0 + wn * 64 + cc * 4] = v;
      }
      __builtin_amdgcn_s_barrier();
    }
  }
}

// ---------------------------------------------------------------------------
// kv + ksum. grid (64 bh, NSPLIT), 256 thr / 4 waves. 2-TERM proj split:
// oh*(khi + klo). phi via single v_exp_f32. (r11 structure, unchanged)
// ---------------------------------------------------------------------------
__global__ __launch_bounds__(256, 2) void kv_mfma(
    const unsigned short* __restrict__ khi, const unsigned short* __restrict__ klo,
    const float* __restrict__ knorms, const unsigned short* __restrict__ vt,
    const unsigned short* __restrict__ orfhi,
    float* __restrict__ pkv, float* __restrict__ pksum) {
  __shared__ __align__(16) unsigned short KsHi[64 * 64], KsLo[64 * 64];
  __shared__ __align__(16) unsigned short VT[64 * 64], KphiT[64 * 64];
  __shared__ float ns[64];
  const int tid = threadIdx.x, lane = tid & 63, w = tid >> 6;
  const int g = lane >> 4, li = lane & 15;
  const int bh = blockIdx.x, sp = blockIdx.y;
  const int srow8 = lane >> 3;
  const int scol  = ((lane & 7) ^ srow8) << 3;
  const int sx = (li & 7) << 3;

  bf16x8 oh[4][2];
#pragma unroll
  for (int p = 0; p < 4; ++p)
#pragma unroll
    for (int kk = 0; kk < 2; ++kk)
      oh[p][kk] = *(const bf16x8*)
          &orfhi[(size_t)(p * 64 + w * 16 + li) * 64 + kk * 32 + g * 8];

  f32x4 kvacc[4][4] = {};
  float ksacc[4][4] = {};

  for (int c = 0; c < LCH / 64; ++c) {
    const int l0 = sp * LCH + c * 64;
    __syncthreads();
    {
      const size_t kb = ((size_t)bh * 4096 + l0 + w * 16 + srow8) * 64 + scol;
      gload16(khi + kb, &KsHi[(w * 16) * 64]);
      gload16(khi + kb + 8 * 64, &KsHi[(w * 16 + 8) * 64]);
      gload16(klo + kb, &KsLo[(w * 16) * 64]);
      gload16(klo + kb + 8 * 64, &KsLo[(w * 16 + 8) * 64]);
      const size_t vb = ((size_t)bh * 64 + w * 16 + srow8) * 4096 + l0 + scol;
      gload16(vt + vb, &VT[(w * 16) * 64]);
      gload16(vt + vb + (size_t)8 * 4096, &VT[(w * 16 + 8) * 64]);
      if (tid < 64) ns[tid] = knorms[(size_t)bh * 4096 + l0 + tid];
    }
    __syncthreads();

#pragma unroll
    for (int p = 0; p < 4; ++p) {
      f32x4 pr[4] = {};
      __builtin_amdgcn_s_setprio(1);
#pragma unroll
      for (int kk = 0; kk < 2; ++kk) {
        const int cx = (kk * 32 + g * 8) ^ sx;
#pragma unroll
        for (int lf = 0; lf < 4; ++lf) {
          const bf16x8 bh2 = *(const bf16x8*)&KsHi[(lf * 16 + li) * 64 + cx];
          const bf16x8 bl2 = *(const bf16x8*)&KsLo[(lf * 16 + li) * 64 + cx];
          pr[lf] = mfma16(oh[p][kk], bh2, pr[lf]);
          pr[lf] = mfma16(oh[p][kk], bl2, pr[lf]);
        }
      }
      __builtin_amdgcn_s_setprio(0);
#pragma unroll
      for (int lf = 0; lf < 4; ++lf) {
        const float nrm = ns[lf * 16 + li];
#pragma unroll
        for (int r = 0; r < 4; ++r) {
          float phi = fexp2(pr[lf][r] - nrm) + EPSF;
          ksacc[p][r] += phi;
          const int row = w * 16 + 4 * g + r;
          KphiT[row * 64 + SWZ(row, lf * 16 + li)] = f2bf(phi);
        }
      }
      __builtin_amdgcn_s_setprio(1);
#pragma unroll
      for (int kk = 0; kk < 2; ++kk) {
        const int cx = (kk * 32 + g * 8) ^ sx;
        const bf16x8 a = *(const bf16x8*)&KphiT[(w * 16 + li) * 64 + cx];
#pragma unroll
        for (int df = 0; df < 4; ++df) {
          const bf16x8 bv = *(const bf16x8*)&VT[(df * 16 + li) * 64 + cx];
          kvacc[p][df] = mfma16(a, bv, kvacc[p][df]);
        }
      }
      __builtin_amdgcn_s_setprio(0);
    }
  }
  float* kvo = pkv + ((size_t)sp * 64 + bh) * (MMF * DK);
#pragma unroll
  for (int p = 0; p < 4; ++p)
#pragma unroll
    for (int df = 0; df < 4; ++df)
#pragma unroll
      for (int r = 0; r < 4; ++r)
        kvo[(p * 64 + w * 16 + 4 * g + r) * DK + df * 16 + li] = kvacc[p][df][r];

  float* kso = pksum + ((size_t)sp * 64 + bh) * MMF;
#pragma unroll
  for (int p = 0; p < 4; ++p)
#pragma unroll
    for (int r = 0; r < 4; ++r) {
      float s = ksacc[p][r];
      s += __shfl_xor(s, 1); s += __shfl_xor(s, 2);
      s += __shfl_xor(s, 4); s += __shfl_xor(s, 8);
      if (li == 0) kso[p * 64 + w * 16 + 4 * g + r] = s;
    }
}

// ---------------------------------------------------------------------------
// reduce partials; emit kv TRANSPOSED bf16 kvT[bh][d][m] + ksum fp32
// ---------------------------------------------------------------------------
__global__ __launch_bounds__(256) void reduce_parts(
    const float* __restrict__ pkv, unsigned short* __restrict__ kvT,
    const float* __restrict__ pks, float* __restrict__ ksg) {
  const int id = blockIdx.x * 256 + threadIdx.x;   // grid 1024 -> 262144
  {
    const int bh = id >> 12, rest = id & 4095;
    const int m0 = (rest >> 6) << 2, d = rest & 63;
    float s0 = 0.f, s1 = 0.f, s2 = 0.f, s3 = 0.f;
#pragma unroll
    for (int sp = 0; sp < NSPLIT; ++sp) {
      const float* p = pkv + (size_t)(sp * 64 + bh) * (MMF * DK) + d;
      s0 += p[(m0 + 0) * DK]; s1 += p[(m0 + 1) * DK];
      s2 += p[(m0 + 2) * DK]; s3 += p[(m0 + 3) * DK];
    }
    ushort4 o;
    o.x = f2bf(s0); o.y = f2bf(s1); o.z = f2bf(s2); o.w = f2bf(s3);
    *(ushort4*)&kvT[((size_t)bh * DK + d) * MMF + m0] = o;
  }
  if (id < 4096) {
    float4 s = {0.f, 0.f, 0.f, 0.f};
#pragma unroll
    for (int sp = 0; sp < NSPLIT; ++sp) {
      float4 v = *(const float4*)&pks[(size_t)sp * 64 * MMF + id * 4];
      s.x += v.x; s.y += v.y; s.z += v.z; s.w += v.w;
    }
    *(float4*)&ksg[id * 4] = s;
  }
}

// ---------------------------------------------------------------------------
// q_phi + num/den -> attn (bf16). grid (64 bh, 32 l-blocks), 512 threads.
// (r11 structure, unchanged)
// ---------------------------------------------------------------------------
__global__ __launch_bounds__(512, 4) void qattn_mfma(
    const unsigned short* __restrict__ qhi, const unsigned short* __restrict__ qlo,
    const float* __restrict__ qnorms,
    const unsigned short* __restrict__ orfhi,
    const unsigned short* __restrict__ kvT, const float* __restrict__ ksg,
    unsigned short* __restrict__ attn) {
  __shared__ __align__(16) unsigned short OHi[256 * 64];    // 32 KB
  __shared__ __align__(16) unsigned short KvTs[64 * 256];   // 32 KB
  __shared__ __align__(16) unsigned short Qphi[8][16 * 64]; // 16 KB
  const int tid = threadIdx.x, lane = tid & 63, w = tid >> 6;
  const int g = lane >> 4, li = lane & 15;
  const int bh = blockIdx.x, lb = blockIdx.y;
  const int b = bh >> 4, h = bh & 15;
  const int srow8 = lane >> 3;
  const int scol  = ((lane & 7) ^ srow8) << 3;
  const int sx = (li & 7) << 3;

#pragma unroll
  for (int q = 0; q < 4; ++q) {
    const size_t o = (size_t)(w * 32 + q * 8 + srow8) * 64 + scol;
    gload16(orfhi + o, &OHi[(w * 32 + q * 8) * 64]);
  }
  {
    const int srow2 = lane >> 5;
#pragma unroll
    for (int q = 0; q < 4; ++q) {
      const int d0 = w * 8 + q * 2, dr = d0 + srow2;
      gload16(kvT + ((size_t)bh * DK + dr) * MMF + (((lane & 31) ^ (dr & 7)) << 3),
              &KvTs[d0 * 256]);
    }
  }

  float ksr[4][4];
#pragma unroll
  for (int p = 0; p < 4; ++p)
#pragma unroll
    for (int mf = 0; mf < 4; ++mf)
      ksr[p][mf] = ksg[(size_t)bh * MMF + p * 64 + mf * 16 + li];
  const float4 nr =
      *(const float4*)&qnorms[(size_t)bh * 4096 + lb * 128 + w * 16 + 4 * g];
  bf16x8 qh[2], ql[2];
  {
    const size_t qr = ((size_t)bh * 4096 + lb * 128 + w * 16 + li) * 64 + g * 8;
    qh[0] = *(const bf16x8*)&qhi[qr];
    qh[1] = *(const bf16x8*)&qhi[qr + 32];
    ql[0] = *(const bf16x8*)&qlo[qr];
    ql[1] = *(const bf16x8*)&qlo[qr + 32];
  }
  __syncthreads();

  f32x4 numacc[4] = {};
  float denacc[4] = {};

#pragma unroll
  for (int p = 0; p < 4; ++p) {
    f32x4 pr[4] = {};
    __builtin_amdgcn_s_setprio(1);
#pragma unroll
    for (int kk = 0; kk < 2; ++kk) {
      const int cx = (kk * 32 + g * 8) ^ sx;
#pragma unroll
      for (int mf = 0; mf < 4; ++mf) {
        const int row = p * 64 + mf * 16 + li;
        const bf16x8 bh2 = *(const bf16x8*)&OHi[row * 64 + cx];
        pr[mf] = mfma16(qh[kk], bh2, pr[mf]);
        pr[mf] = mfma16(ql[kk], bh2, pr[mf]);
      }
    }
    __builtin_amdgcn_s_setprio(0);
#pragma unroll
    for (int mf = 0; mf < 4; ++mf) {
      const float ks = ksr[p][mf];
#pragma unroll
      for (int r = 0; r < 4; ++r) {
        float phi = fexp2(pr[mf][r] - nr[r]) + EPSF;
        denacc[r] += phi * ks;
        const int row = 4 * g + r;
        Qphi[w][row * 64 + SWZ(row, mf * 16 + li)] = f2bf(phi);
      }
    }
    __builtin_amdgcn_s_setprio(1);
#pragma unroll
    for (int kk = 0; kk < 2; ++kk) {
      const int cx = (kk * 32 + g * 8) ^ sx;
      const bf16x8 a = *(const bf16x8*)&Qphi[w][li * 64 + cx];
#pragma unroll
      for (int df = 0; df < 4; ++df) {
        const bf16x8 bv = *(const bf16x8*)
            &KvTs[(df * 16 + li) * 256 + (((p * 8 + kk * 4 + g) ^ (li & 7)) << 3)];
        numacc[df] = mfma16(a, bv, numacc[df]);
      }
    }
    __builtin_amdgcn_s_setprio(0);
  }
  float den[4];
#pragma unroll
  for (int r = 0; r < 4; ++r) {
    float s = denacc[r];
    s += __shfl_xor(s, 1); s += __shfl_xor(s, 2);
    s += __shfl_xor(s, 4); s += __shfl_xor(s, 8);
    den[r] = s;
  }
  unsigned short* ab =
      attn + ((size_t)b * 4096 + lb * 128) * 1024 + h * 64;
#pragma unroll
  for (int df = 0; df < 4; ++df)
#pragma unroll
    for (int r = 0; r < 4; ++r)
      ab[(size_t)(w * 16 + 4 * g + r) * 1024 + df * 16 + li] =
          f2bf(numacc[df][r] / den[r]);
}

// ---------------------------------------------------------------------------
extern "C" void kernel_launch(void* const* d_in, const int* in_sizes, int n_in,
                              void* d_out, int out_size, void* d_ws, size_t ws_size,
                              hipStream_t stream) {
  (void)in_sizes; (void)n_in; (void)out_size; (void)ws_size;
  const float* x   = (const float*)d_in[0];
  const float* Wq  = (const float*)d_in[1];
  const float* bq  = (const float*)d_in[2];
  const float* Wk  = (const float*)d_in[3];
  const float* bk  = (const float*)d_in[4];
  const float* Wv  = (const float*)d_in[5];
  const float* bv  = (const float*)d_in[6];
  const float* Wo  = (const float*)d_in[7];
  const float* bo  = (const float*)d_in[8];
  const float* orf = (const float*)d_in[9];
  float* out = (float*)d_out;

  const size_t ND = (size_t)BB * LL * DD;   // 16,777,216
  char* base = (char*)d_ws;
  size_t off = 0;
  auto alloc = [&](size_t bytes) -> char* {
    char* p = base + off;
    off += (bytes + 255) & ~(size_t)255;
    return p;
  };
  unsigned short* wqbf   = (unsigned short*)alloc((size_t)DD * DD * 2);
  unsigned short* wkbf   = (unsigned short*)alloc((size_t)DD * DD * 2);
  unsigned short* wvbf   = (unsigned short*)alloc((size_t)DD * DD * 2);
  unsigned short* wobf   = (unsigned short*)alloc((size_t)DD * DD * 2);
  unsigned short* orfhi  = (unsigned short*)alloc((size_t)MMF * DK * 2);
  unsigned short* xbf    = (unsigned short*)alloc(ND * 2);   // aliased by pkv
  unsigned short* qhi    = (unsigned short*)alloc(ND * 2);
  unsigned short* qlo    = (unsigned short*)alloc(ND * 2);
  unsigned short* khi    = (unsigned short*)alloc(ND * 2);   // aliased by attnbf
  unsigned short* klo    = (unsigned short*)alloc(ND * 2);
  unsigned short* vtbuf  = (unsigned short*)alloc(ND * 2);
  float*          qnorms = (float*)alloc((size_t)64 * LL * 4);
  float*          knorms = (float*)alloc((size_t)64 * LL * 4);
  float*          pksum  = (float*)alloc((size_t)NSPLIT * 64 * MMF * 4);
  unsigned short* kvT    = (unsigned short*)alloc((size_t)64 * DK * MMF * 2);
  float*          ksg    = (float*)alloc((size_t)64 * MMF * 4);
  float*          pkv    = (float*)xbf;            // 33.5 MB, exact alias
  unsigned short* attnbf = khi;                    // khi dead after kv_mfma

  cvt_bf16<<<16384, 256, 0, stream>>>(x, xbf, (int)ND);
  cvt_bf16_w<<<dim3(1024, 4), 256, 0, stream>>>(Wq, Wk, Wv, Wo,
                                                wqbf, wkbf, wvbf, wobf);
  cvt_orf<<<64, 256, 0, stream>>>(orf, orfhi, MMF * DK);

  dim3 gg(64, 4);
  gemm_mfma<2><<<gg, 512, 0, stream>>>(xbf, wqbf, bq, (float*)0, qhi, qlo,
                                       qnorms, BB * LL, DD, DD);
  gemm_mfma<2><<<gg, 512, 0, stream>>>(xbf, wkbf, bk, (float*)0, khi, klo,
                                       knorms, BB * LL, DD, DD);
  gemm_mfma<1><<<gg, 512, 0, stream>>>(xbf, wvbf, bv, (float*)0, vtbuf,
                                       (unsigned short*)0, (float*)0,
                                       BB * LL, DD, DD);

  kv_mfma<<<dim3(64, NSPLIT), 256, 0, stream>>>(khi, klo, knorms, vtbuf,
                                                orfhi, pkv, pksum);
  reduce_parts<<<1024, 256, 0, stream>>>(pkv, kvT, pksum, ksg);
  qattn_mfma<<<dim3(64, 32), 512, 0, stream>>>(qhi, qlo, qnorms, orfhi,
                                               kvT, ksg, attnbf);

  gemm_mfma<0><<<gg, 512, 0, stream>>>(attnbf, wobf, bo, out, (unsigned short*)0,
                                       (unsigned short*)0, (float*)0,
                                       BB * LL, DD, DD);
}